// Round 4
// baseline (343.060 us; speedup 1.0000x reference)
//
#include <hip/hip_runtime.h>
#include <math.h>

#define N 16384
#define D 64
#define NCB 16    // candidate slices for KNN (1024 candidates each)
#define CHUNK 1024
#define QPT 2     // queries per thread in knnA/knnB

__device__ __forceinline__ float wsum(float v){
  #pragma unroll
  for(int m=32;m>0;m>>=1) v += __shfl_xor(v,m,64);
  return v;
}

// ---- Kernel 1: LN -> x2 -> LN, row L2 norms, and c4=(x,y,z,sq) prep. ----
__global__ __launch_bounds__(256) void ln_kernel(const float* __restrict__ in,
    const float* __restrict__ g1,const float* __restrict__ b1,
    const float* __restrict__ g2,const float* __restrict__ b2,
    const float* __restrict__ coords,
    float* __restrict__ x, float* __restrict__ xn, float4* __restrict__ c4){
  int wave=threadIdx.x>>6, lane=threadIdx.x&63;
  int row=blockIdx.x*4+wave;
  float v=in[row*64+lane];
  float m=wsum(v)*(1.0f/64.0f);
  float d=v-m;
  float var=wsum(d*d)*(1.0f/64.0f);
  float y=d*(1.0f/sqrtf(var+1e-5f))*g1[lane]+b1[lane];
  y=y+y;  // transformer stubbed as identity + shortcut
  float m2=wsum(y)*(1.0f/64.0f);
  float d2=y-m2;
  float var2=wsum(d2*d2)*(1.0f/64.0f);
  float z=d2*(1.0f/sqrtf(var2+1e-5f))*g2[lane]+b2[lane];
  x[row*64+lane]=z;
  float s=wsum(z*z);
  if(lane==0){
    xn[row]=fmaxf(sqrtf(s),1e-8f);
    // candidate prep: sq with the reference's exact rounding sequence
    float a=coords[row*3+0],b=coords[row*3+1],c=coords[row*3+2];
    float sq=__fadd_rn(__fadd_rn(__fmul_rn(a,a),__fmul_rn(b,b)),__fmul_rn(c,c));
    c4[row]=make_float4(a,b,c,sq);
  }
}

// ---- KNN pass A: per-slice top-3 DISTANCES only, candidates via SGPRs. ----
// j2 is wave-uniform -> s_load_dwordx4 through the scalar cache; each VALU op
// reads <=1 SGPR. Hot pair cost: mul+fma+fma (dot) + add (sc) + fma (dd)
// + med3+med3+min (insert) = 8 VALU, zero LDS.
// dd = fma(-2,dot, sq_i+sq_j) == rn(sc - 2*dot) (2*dot exact) — bit-identical
// to the passing round-2/3 arithmetic.
__global__ __launch_bounds__(256) void knnA(const float4* __restrict__ c4,
    float* __restrict__ pdist){
  int tid=threadIdx.x, qb=blockIdx.x, cs=blockIdx.y;
  float qx[QPT],qy[QPT],qz[QPT],qs[QPT];
  float t0[QPT],t1[QPT],t2[QPT]; int qidx[QPT];
  #pragma unroll
  for(int qq=0;qq<QPT;qq++){
    int q=qb*(256*QPT)+qq*256+tid;
    qidx[qq]=q;
    float4 v=c4[q];
    qx[qq]=v.x; qy[qq]=v.y; qz[qq]=v.z; qs[qq]=v.w;
    t0[qq]=1e30f; t1[qq]=1e30f; t2[qq]=1e30f;
  }
  int cbase=cs*CHUNK;
  // overlap between this block's queries [qb*512,+512) and candidates
  // [cs*1024,+1024) exists iff (qb>>1)==cs — scalar branch, two loop variants.
  if((qb>>1)==cs){
    #pragma unroll 8
    for(int j=0;j<CHUNK;j++){
      int j2=__builtin_amdgcn_readfirstlane(cbase+j);
      float4 cv=c4[j2];
      #pragma unroll
      for(int qq=0;qq<QPT;qq++){
        float dot=__fmaf_rn(qz[qq],cv.z,__fmaf_rn(qy[qq],cv.y,__fmul_rn(qx[qq],cv.x)));
        float sc =__fadd_rn(qs[qq],cv.w);
        float dd =__fmaf_rn(-2.0f,dot,sc);
        dd = (j2==qidx[qq]) ? 1e30f : dd;      // exclude self
        t2[qq]=__builtin_amdgcn_fmed3f(t1[qq],t2[qq],dd);
        t1[qq]=__builtin_amdgcn_fmed3f(t0[qq],t1[qq],dd);
        t0[qq]=fminf(t0[qq],dd);
      }
    }
  } else {
    #pragma unroll 8
    for(int j=0;j<CHUNK;j++){
      int j2=__builtin_amdgcn_readfirstlane(cbase+j);
      float4 cv=c4[j2];
      #pragma unroll
      for(int qq=0;qq<QPT;qq++){
        float dot=__fmaf_rn(qz[qq],cv.z,__fmaf_rn(qy[qq],cv.y,__fmul_rn(qx[qq],cv.x)));
        float sc =__fadd_rn(qs[qq],cv.w);
        float dd =__fmaf_rn(-2.0f,dot,sc);
        t2[qq]=__builtin_amdgcn_fmed3f(t1[qq],t2[qq],dd);
        t1[qq]=__builtin_amdgcn_fmed3f(t0[qq],t1[qq],dd);
        t0[qq]=fminf(t0[qq],dd);
      }
    }
  }
  #pragma unroll
  for(int qq=0;qq<QPT;qq++){
    size_t base=((size_t)cs*N+qidx[qq])*3;
    pdist[base+0]=t0[qq]; pdist[base+1]=t1[qq]; pdist[base+2]=t2[qq];
  }
}

// ---- KNN merge: global 3rd-smallest distance per query -> threshold. ----
// Also zeroes the pass-B hit counters (stream-ordered before knnB).
__global__ __launch_bounds__(256) void knnA_merge(const float* __restrict__ pdist,
    float* __restrict__ thr, int* __restrict__ cnt){
  int q=blockIdx.x*256+threadIdx.x;
  float t0=1e30f,t1=1e30f,t2=1e30f;
  for(int s=0;s<NCB;s++){
    size_t base=((size_t)s*N+q)*3;
    #pragma unroll
    for(int m=0;m<3;m++){
      float d=pdist[base+m];
      t2=__builtin_amdgcn_fmed3f(t1,t2,d);
      t1=__builtin_amdgcn_fmed3f(t0,t1,d);
      t0=fminf(t0,d);
    }
  }
  thr[q]=t2; cnt[q]=0;
}

// ---- KNN pass B: recover indices. Hot path = 5 VALU dist + 1 cmp. ----
// Rare path (~4 hits/query over the whole scan) appends (idx, dd) to an
// 8-slot per-query list. Self lands in the rare path (dd_self ~ 1e-7 <= thr)
// and is excluded there.
__global__ __launch_bounds__(256) void knnB(const float4* __restrict__ c4,
    const float* __restrict__ thr, int* __restrict__ cnt,
    int* __restrict__ hit_i, float* __restrict__ hit_d){
  int tid=threadIdx.x, qb=blockIdx.x, cs=blockIdx.y;
  float qx[QPT],qy[QPT],qz[QPT],qs[QPT],tq[QPT]; int qidx[QPT];
  #pragma unroll
  for(int qq=0;qq<QPT;qq++){
    int q=qb*(256*QPT)+qq*256+tid;
    qidx[qq]=q;
    float4 v=c4[q];
    qx[qq]=v.x; qy[qq]=v.y; qz[qq]=v.z; qs[qq]=v.w;
    tq[qq]=thr[q];
  }
  int cbase=cs*CHUNK;
  #pragma unroll 8
  for(int j=0;j<CHUNK;j++){
    int j2=__builtin_amdgcn_readfirstlane(cbase+j);
    float4 cv=c4[j2];
    #pragma unroll
    for(int qq=0;qq<QPT;qq++){
      float dot=__fmaf_rn(qz[qq],cv.z,__fmaf_rn(qy[qq],cv.y,__fmul_rn(qx[qq],cv.x)));
      float sc =__fadd_rn(qs[qq],cv.w);
      float dd =__fmaf_rn(-2.0f,dot,sc);
      if(dd<=tq[qq]){
        int q=qidx[qq];
        if(j2!=q){
          int slot=atomicAdd(&cnt[q],1);
          if(slot<8){ hit_i[q*8+slot]=j2; hit_d[q*8+slot]=dd; }
        }
      }
    }
  }
}

// ---- Final select (lexicographic (d,idx) over <=8 hits) fused with
//      edge weights sigmoid(cos-sim) + dis = 1/sqrt(deg). Wave/node. ----
__global__ __launch_bounds__(256) void ew_kernel(const float* __restrict__ x,
    const float* __restrict__ xn, const int* __restrict__ cnt,
    const int* __restrict__ hit_i, const float* __restrict__ hit_d,
    int* __restrict__ knn, float* __restrict__ ew, float* __restrict__ dis){
  int wave=threadIdx.x>>6, lane=threadIdx.x&63;
  int i=blockIdx.x*4+wave;
  int c=min(cnt[i],8);                 // wave-uniform -> no divergence
  float D0=1e30f,D1=1e30f,D2=1e30f; int I0=i,I1=i,I2=i;
  for(int m=0;m<c;m++){
    float d=hit_d[i*8+m]; int ix=hit_i[i*8+m];   // same-addr broadcast loads
    bool lt2=(d<D2)||((d==D2)&&(ix<I2));
    if(lt2){
      bool lt1=(d<D1)||((d==D1)&&(ix<I1));
      if(lt1){
        D2=D1; I2=I1;
        bool lt0=(d<D0)||((d==D0)&&(ix<I0));
        if(lt0){ D1=D0; I1=I0; D0=d; I0=ix; }
        else   { D1=d; I1=ix; }
      } else { D2=d; I2=ix; }
    }
  }
  if(lane==0){ knn[i*3+0]=I0; knn[i*3+1]=I1; knn[i*3+2]=I2; }
  float xi=x[i*64+lane];
  float ni=xn[i];
  float ssum=0.f;
  int ss[3]={I0,I1,I2};
  #pragma unroll
  for(int m=0;m<3;m++){
    int s=ss[m];
    float xs=x[s*64+lane];
    float dot=wsum(xs*xi);
    float cv=dot/(xn[s]*ni);
    float e=1.f/(1.f+expf(-cv));
    if(lane==0) ew[i*3+m]=e;
    ssum+=e;
  }
  if(lane==0) dis[i]=1.f/sqrtf(ssum+1.0f);  // deg = 1 (self loop) + sum(ew)
}

// ---- H = X * W (16384x64 @ 64x64 fp32, vector ALU). ----
__global__ __launch_bounds__(256) void gemm64(const float* __restrict__ X,
    const float* __restrict__ W, float* __restrict__ H){
  __shared__ float Ws[4096];
  int tid=threadIdx.x;
  for(int k=tid;k<4096;k+=256) Ws[k]=W[k];
  __syncthreads();
  int wave=tid>>6, lane=tid&63;
  int r0=(blockIdx.x*4+wave)*4;
  const float4* X4=(const float4*)X;
  float acc[4]={0.f,0.f,0.f,0.f};
  #pragma unroll
  for(int k4=0;k4<16;k4++){
    float w0=Ws[(k4*4+0)*64+lane];
    float w1=Ws[(k4*4+1)*64+lane];
    float w2=Ws[(k4*4+2)*64+lane];
    float w3=Ws[(k4*4+3)*64+lane];
    #pragma unroll
    for(int rr=0;rr<4;rr++){
      float4 xv=X4[(r0+rr)*16+k4];
      acc[rr]=fmaf(xv.x,w0,acc[rr]);
      acc[rr]=fmaf(xv.y,w1,acc[rr]);
      acc[rr]=fmaf(xv.z,w2,acc[rr]);
      acc[rr]=fmaf(xv.w,w3,acc[rr]);
    }
  }
  #pragma unroll
  for(int rr=0;rr<4;rr++) H[(r0+rr)*64+lane]=acc[rr];
}

// ---- GCN aggregate (gather: 3 nbrs + self) + bias + LN + ReLU. ----
__global__ __launch_bounds__(256) void agg1_kernel(const float* __restrict__ h,
    const float* __restrict__ ew, const float* __restrict__ dis, const int* __restrict__ knn,
    const float* __restrict__ bias, const float* __restrict__ gg, const float* __restrict__ gb,
    float* __restrict__ out){
  int wave=threadIdx.x>>6, lane=threadIdx.x&63;
  int i=blockIdx.x*4+wave;
  float di=dis[i];
  float acc=h[i*64+lane]*(di*di);           // self loop, ew=1
  #pragma unroll
  for(int m=0;m<3;m++){
    int s=knn[i*3+m];
    acc+=h[s*64+lane]*(dis[s]*ew[i*3+m]*di);
  }
  acc+=bias[lane];
  float mu=wsum(acc)*(1.0f/64.0f);
  float dd=acc-mu;
  float var=wsum(dd*dd)*(1.0f/64.0f);
  float y=dd*(1.0f/sqrtf(var+1e-5f))*gg[lane]+gb[lane];
  out[i*64+lane]=fmaxf(y,0.0f);
}

// ---- Second GCN aggregate + bias + residual (out = 2x + gcn2). ----
__global__ __launch_bounds__(256) void agg2_kernel(const float* __restrict__ h,
    const float* __restrict__ ew, const float* __restrict__ dis, const int* __restrict__ knn,
    const float* __restrict__ bias, const float* __restrict__ x,
    float* __restrict__ out){
  int wave=threadIdx.x>>6, lane=threadIdx.x&63;
  int i=blockIdx.x*4+wave;
  float di=dis[i];
  float acc=h[i*64+lane]*(di*di);
  #pragma unroll
  for(int m=0;m<3;m++){
    int s=knn[i*3+m];
    acc+=h[s*64+lane]*(dis[s]*ew[i*3+m]*di);
  }
  acc+=bias[lane];
  float xv=x[i*64+lane];
  out[i*64+lane]=(acc+xv)+xv;  // (gcn2 + x) + shortcut, shortcut == x
}

extern "C" void kernel_launch(void* const* d_in, const int* in_sizes, int n_in,
                              void* d_out, int out_size, void* d_ws, size_t ws_size,
                              hipStream_t stream){
  const float* feat  =(const float*)d_in[0];
  // d_in[1] edge_index_tran, d_in[2] edge_attr_rpe, d_in[3] norm_index: unused by reference
  const float* coords=(const float*)d_in[4];
  const float* g1 =(const float*)d_in[5];
  const float* b1n=(const float*)d_in[6];
  const float* g2 =(const float*)d_in[7];
  const float* b2n=(const float*)d_in[8];
  const float* gg =(const float*)d_in[9];
  const float* gb =(const float*)d_in[10];
  const float* W1 =(const float*)d_in[11];
  const float* bb1=(const float*)d_in[12];
  const float* W2 =(const float*)d_in[13];
  const float* bb2=(const float*)d_in[14];
  float* out=(float*)d_out;

  char* ws=(char*)d_ws;
  size_t o=0;
  float*  x    =(float*) (ws+o); o+=(size_t)N*64*4;      // post-LN2 features
  float*  h    =(float*) (ws+o); o+=(size_t)N*64*4;      // GEMM output (reused)
  float*  a1   =(float*) (ws+o); o+=(size_t)N*64*4;      // activated GCN1 output
  float*  xn   =(float*) (ws+o); o+=(size_t)N*4;         // row norms of x
  float*  ew   =(float*) (ws+o); o+=(size_t)N*3*4;       // knn edge weights
  float*  dis  =(float*) (ws+o); o+=(size_t)N*4;         // 1/sqrt(deg)
  int*    knn  =(int*)   (ws+o); o+=(size_t)N*3*4;       // neighbor indices
  float4* c4   =(float4*)(ws+o); o+=(size_t)N*16;        // (x,y,z,sq) candidates
  float*  pdist=(float*) (ws+o); o+=(size_t)NCB*N*3*4;   // per-slice top-3 dists
  float*  thr  =(float*) (ws+o); o+=(size_t)N*4;         // global 3rd-best dist
  int*    cnt  =(int*)   (ws+o); o+=(size_t)N*4;         // hit counters
  int*    hit_i=(int*)   (ws+o); o+=(size_t)N*8*4;       // hit indices (8 slots)
  float*  hit_d=(float*) (ws+o); o+=(size_t)N*8*4;       // hit distances
  (void)ws_size; (void)in_sizes; (void)n_in; (void)out_size;

  hipLaunchKernelGGL(ln_kernel,   dim3(N/4),    dim3(256), 0, stream, feat,g1,b1n,g2,b2n,coords,x,xn,c4);
  hipLaunchKernelGGL(knnA,        dim3(32,NCB), dim3(256), 0, stream, c4,pdist);
  hipLaunchKernelGGL(knnA_merge,  dim3(N/256),  dim3(256), 0, stream, pdist,thr,cnt);
  hipLaunchKernelGGL(knnB,        dim3(32,NCB), dim3(256), 0, stream, c4,thr,cnt,hit_i,hit_d);
  hipLaunchKernelGGL(ew_kernel,   dim3(N/4),    dim3(256), 0, stream, x,xn,cnt,hit_i,hit_d,knn,ew,dis);
  hipLaunchKernelGGL(gemm64,      dim3(N/16),   dim3(256), 0, stream, x,W1,h);
  hipLaunchKernelGGL(agg1_kernel, dim3(N/4),    dim3(256), 0, stream, h,ew,dis,knn,bb1,gg,gb,a1);
  hipLaunchKernelGGL(gemm64,      dim3(N/16),   dim3(256), 0, stream, a1,W2,h);
  hipLaunchKernelGGL(agg2_kernel, dim3(N/4),    dim3(256), 0, stream, h,ew,dis,knn,bb2,x,out);
}

// Round 5
// 268.263 us; speedup vs baseline: 1.2788x; 1.2788x over previous
//
#include <hip/hip_runtime.h>
#include <math.h>

#define N 16384
#define D 64
#define GC 16            // grid cells per dim
#define NCELL (GC*GC*GC) // 4096

__device__ __forceinline__ float wsum(float v){
  #pragma unroll
  for(int m=32;m>0;m>>=1) v += __shfl_xor(v,m,64);
  return v;
}

// branchless lexicographic (d,idx) top-3 insert; matches jax top_k stable tie-break
__device__ __forceinline__ void lexins(float dd,int j2,
    float&D0,float&D1,float&D2,int&I0,int&I1,int&I2){
  bool lt0=(dd<D0)||((dd==D0)&&(j2<I0));
  bool lt1=(dd<D1)||((dd==D1)&&(j2<I1));
  bool lt2=(dd<D2)||((dd==D2)&&(j2<I2));
  float nD2=lt1?D1:(lt2?dd:D2); int nI2=lt1?I1:(lt2?j2:I2);
  float nD1=lt0?D0:(lt1?dd:D1); int nI1=lt0?I0:(lt1?j2:I1);
  float nD0=lt0?dd:D0;          int nI0=lt0?j2:I0;
  D0=nD0;D1=nD1;D2=nD2;I0=nI0;I1=nI1;I2=nI2;
}

// reference-exact squared distance: dd = rn(rn(qs+cs) - 2*dot), dot FMA chain
__device__ __forceinline__ float refdist(float qx,float qy,float qz,float qs,float4 cv){
  float dot=__fmaf_rn(qz,cv.z,__fmaf_rn(qy,cv.y,__fmul_rn(qx,cv.x)));
  float sc =__fadd_rn(qs,cv.w);
  return __fmaf_rn(-2.0f,dot,sc);
}

// ---- Kernel 1: LN -> x2 -> LN, row L2 norms, c4=(x,y,z,sq), cell histogram. ----
__global__ __launch_bounds__(256) void ln_kernel(const float* __restrict__ in,
    const float* __restrict__ g1,const float* __restrict__ b1,
    const float* __restrict__ g2,const float* __restrict__ b2,
    const float* __restrict__ coords,
    float* __restrict__ x, float* __restrict__ xn, float4* __restrict__ c4,
    int* __restrict__ cellCnt){
  int wave=threadIdx.x>>6, lane=threadIdx.x&63;
  int row=blockIdx.x*4+wave;
  float v=in[row*64+lane];
  float m=wsum(v)*(1.0f/64.0f);
  float d=v-m;
  float var=wsum(d*d)*(1.0f/64.0f);
  float y=d*(1.0f/sqrtf(var+1e-5f))*g1[lane]+b1[lane];
  y=y+y;  // transformer stubbed as identity + shortcut
  float m2=wsum(y)*(1.0f/64.0f);
  float d2=y-m2;
  float var2=wsum(d2*d2)*(1.0f/64.0f);
  float z=d2*(1.0f/sqrtf(var2+1e-5f))*g2[lane]+b2[lane];
  x[row*64+lane]=z;
  float s=wsum(z*z);
  if(lane==0){
    xn[row]=fmaxf(sqrtf(s),1e-8f);
    float a=coords[row*3+0],b=coords[row*3+1],c=coords[row*3+2];
    float sq=__fadd_rn(__fadd_rn(__fmul_rn(a,a),__fmul_rn(b,b)),__fmul_rn(c,c));
    c4[row]=make_float4(a,b,c,sq);
    int cx=min(GC-1,(int)(a*(float)GC)), cy=min(GC-1,(int)(b*(float)GC)),
        cz=min(GC-1,(int)(c*(float)GC));
    atomicAdd(&cellCnt[(cz*GC+cy)*GC+cx],1);
  }
}

// ---- Kernel 2: exclusive prefix sum over 4096 cell counts (single block). ----
__global__ __launch_bounds__(256) void scan_kernel(const int* __restrict__ cnt,
    int* __restrict__ start, int* __restrict__ cur){
  __shared__ int part[256];
  int tid=threadIdx.x, base=tid*16, s=0, loc[16];
  #pragma unroll
  for(int k=0;k<16;k++){ loc[k]=s; s+=cnt[base+k]; }
  part[tid]=s; __syncthreads();
  for(int off=1;off<256;off<<=1){
    int t=(tid>=off)?part[tid-off]:0;
    __syncthreads();
    part[tid]+=t;
    __syncthreads();
  }
  int excl=part[tid]-s;
  #pragma unroll
  for(int k=0;k<16;k++){ start[base+k]=excl+loc[k]; cur[base+k]=excl+loc[k]; }
  if(tid==255) start[NCELL]=part[255];
}

// ---- Kernel 3: scatter points into cell-sorted order. ----
__global__ __launch_bounds__(256) void scatter_kernel(const float4* __restrict__ c4,
    int* __restrict__ cur, float4* __restrict__ sc4, int* __restrict__ sidx){
  int t=blockIdx.x*256+threadIdx.x;
  float4 v=c4[t];
  int cx=min(GC-1,(int)(v.x*(float)GC)), cy=min(GC-1,(int)(v.y*(float)GC)),
      cz=min(GC-1,(int)(v.z*(float)GC));
  int pos=atomicAdd(&cur[(cz*GC+cy)*GC+cx],1);
  sc4[pos]=v; sidx[pos]=t;
}

// ---- Kernel 4: grid KNN. 4 lanes per query, 9 x-merged cell runs split
//      across the 4 lanes, lex top-3 merged via 2 butterfly steps. Exact
//      unless the 3x3x3 region provably might miss a neighbor -> flag. ----
__global__ __launch_bounds__(256) void knn_grid(const float4* __restrict__ sc4,
    const int* __restrict__ sidx, const int* __restrict__ cstart,
    int* __restrict__ knn, int* __restrict__ flag){
  int gt=blockIdx.x*256+threadIdx.x;
  int slot=gt>>2, part=gt&3;
  float4 qv=sc4[slot]; int q=sidx[slot];
  float qx=qv.x,qy=qv.y,qz=qv.z,qs=qv.w;
  int cx=min(GC-1,(int)(qx*(float)GC)), cy=min(GC-1,(int)(qy*(float)GC)),
      cz=min(GC-1,(int)(qz*(float)GC));
  float D0=1e30f,D1=1e30f,D2=1e30f; int I0=0x7fffffff,I1=0x7fffffff,I2=0x7fffffff;
  int xlo=max(cx-1,0), xhi=min(cx+1,GC-1);
  for(int r=part;r<9;r+=4){
    int z2=cz+r/3-1, y2=cy+r%3-1;
    if(z2<0||z2>=GC||y2<0||y2>=GC) continue;
    int rowb=(z2*GC+y2)*GC;
    int p0=cstart[rowb+xlo], p1=cstart[rowb+xhi+1];  // x-cells contiguous
    for(int p=p0;p<p1;p++){
      float4 cv=sc4[p]; int j2=sidx[p];
      float dd=refdist(qx,qy,qz,qs,cv);
      dd=(j2==q)?1e30f:dd;
      lexins(dd,j2,D0,D1,D2,I0,I1,I2);
    }
  }
  // merge the 4 partials (lanes 4k..4k+3 hold the same query)
  #pragma unroll
  for(int m=1;m<4;m<<=1){
    float e0=__shfl_xor(D0,m),e1=__shfl_xor(D1,m),e2=__shfl_xor(D2,m);
    int   f0=__shfl_xor(I0,m),f1=__shfl_xor(I1,m),f2=__shfl_xor(I2,m);
    lexins(e0,f0,D0,D1,D2,I0,I1,I2);
    lexins(e1,f1,D0,D1,D2,I0,I1,I2);
    lexins(e2,f2,D0,D1,D2,I0,I1,I2);
  }
  if(part==0){
    // completeness margin: min distance from q to boundary of searched region
    const float cw=1.0f/(float)GC;
    float mg=1e30f;
    mg=fminf(mg,(cx>0)?(qx-(float)(cx-1)*cw):1e30f);
    mg=fminf(mg,(cx<GC-1)?((float)(cx+2)*cw-qx):1e30f);
    mg=fminf(mg,(cy>0)?(qy-(float)(cy-1)*cw):1e30f);
    mg=fminf(mg,(cy<GC-1)?((float)(cy+2)*cw-qy):1e30f);
    mg=fminf(mg,(cz>0)?(qz-(float)(cz-1)*cw):1e30f);
    mg=fminf(mg,(cz<GC-1)?((float)(cz+2)*cw-qz):1e30f);
    float mg2=mg*mg*(1.0f-1e-5f);   // slack for dd rounding
    flag[q]=(D2<mg2)?0:1;
    knn[q*3+0]=I0; knn[q*3+1]=I1; knn[q*3+2]=I2;
  }
}

// ---- Kernel 5: brute-force fallback for flagged queries (wave-cooperative).
//      Expected ~0 flagged; each wave handles its 64 queries' flags. ----
__global__ __launch_bounds__(256) void knn_fb(const float4* __restrict__ c4,
    const int* __restrict__ flag, int* __restrict__ knn){
  int wave=threadIdx.x>>6, lane=threadIdx.x&63;
  int qbase=blockIdx.x*256+wave*64;
  unsigned long long mask=__ballot(flag[qbase+lane]!=0);
  while(mask){
    int b=__ffsll(mask)-1; mask&=mask-1;
    int q=qbase+b;
    float4 qv=c4[q];
    float D0=1e30f,D1=1e30f,D2=1e30f; int I0=0x7fffffff,I1=0x7fffffff,I2=0x7fffffff;
    for(int j=lane;j<N;j+=64){
      float4 cv=c4[j];
      float dd=refdist(qv.x,qv.y,qv.z,qv.w,cv);
      dd=(j==q)?1e30f:dd;
      lexins(dd,j,D0,D1,D2,I0,I1,I2);
    }
    #pragma unroll
    for(int m=1;m<64;m<<=1){
      float e0=__shfl_xor(D0,m),e1=__shfl_xor(D1,m),e2=__shfl_xor(D2,m);
      int   f0=__shfl_xor(I0,m),f1=__shfl_xor(I1,m),f2=__shfl_xor(I2,m);
      lexins(e0,f0,D0,D1,D2,I0,I1,I2);
      lexins(e1,f1,D0,D1,D2,I0,I1,I2);
      lexins(e2,f2,D0,D1,D2,I0,I1,I2);
    }
    if(lane==0){ knn[q*3+0]=I0; knn[q*3+1]=I1; knn[q*3+2]=I2; }
  }
}

// ---- Edge weights sigmoid(cos-sim) + dis = 1/sqrt(deg). Wave/node. ----
__global__ __launch_bounds__(256) void ew_kernel(const float* __restrict__ x,
    const float* __restrict__ xn, const int* __restrict__ knn,
    float* __restrict__ ew, float* __restrict__ dis){
  int wave=threadIdx.x>>6, lane=threadIdx.x&63;
  int i=blockIdx.x*4+wave;
  float xi=x[i*64+lane];
  float ni=xn[i];
  float ssum=0.f;
  #pragma unroll
  for(int m=0;m<3;m++){
    int s=knn[i*3+m];
    float xs=x[s*64+lane];
    float dot=wsum(xs*xi);
    float cv=dot/(xn[s]*ni);
    float e=1.f/(1.f+expf(-cv));
    if(lane==0) ew[i*3+m]=e;
    ssum+=e;
  }
  if(lane==0) dis[i]=1.f/sqrtf(ssum+1.0f);  // deg = 1 (self loop) + sum(ew)
}

// ---- H = X * W (16384x64 @ 64x64 fp32, vector ALU). ----
__global__ __launch_bounds__(256) void gemm64(const float* __restrict__ X,
    const float* __restrict__ W, float* __restrict__ H){
  __shared__ float Ws[4096];
  int tid=threadIdx.x;
  for(int k=tid;k<4096;k+=256) Ws[k]=W[k];
  __syncthreads();
  int wave=tid>>6, lane=tid&63;
  int r0=(blockIdx.x*4+wave)*4;
  const float4* X4=(const float4*)X;
  float acc[4]={0.f,0.f,0.f,0.f};
  #pragma unroll
  for(int k4=0;k4<16;k4++){
    float w0=Ws[(k4*4+0)*64+lane];
    float w1=Ws[(k4*4+1)*64+lane];
    float w2=Ws[(k4*4+2)*64+lane];
    float w3=Ws[(k4*4+3)*64+lane];
    #pragma unroll
    for(int rr=0;rr<4;rr++){
      float4 xv=X4[(r0+rr)*16+k4];
      acc[rr]=fmaf(xv.x,w0,acc[rr]);
      acc[rr]=fmaf(xv.y,w1,acc[rr]);
      acc[rr]=fmaf(xv.z,w2,acc[rr]);
      acc[rr]=fmaf(xv.w,w3,acc[rr]);
    }
  }
  #pragma unroll
  for(int rr=0;rr<4;rr++) H[(r0+rr)*64+lane]=acc[rr];
}

// ---- GCN aggregate (gather: 3 nbrs + self) + bias + LN + ReLU. ----
__global__ __launch_bounds__(256) void agg1_kernel(const float* __restrict__ h,
    const float* __restrict__ ew, const float* __restrict__ dis, const int* __restrict__ knn,
    const float* __restrict__ bias, const float* __restrict__ gg, const float* __restrict__ gb,
    float* __restrict__ out){
  int wave=threadIdx.x>>6, lane=threadIdx.x&63;
  int i=blockIdx.x*4+wave;
  float di=dis[i];
  float acc=h[i*64+lane]*(di*di);           // self loop, ew=1
  #pragma unroll
  for(int m=0;m<3;m++){
    int s=knn[i*3+m];
    acc+=h[s*64+lane]*(dis[s]*ew[i*3+m]*di);
  }
  acc+=bias[lane];
  float mu=wsum(acc)*(1.0f/64.0f);
  float dd=acc-mu;
  float var=wsum(dd*dd)*(1.0f/64.0f);
  float y=dd*(1.0f/sqrtf(var+1e-5f))*gg[lane]+gb[lane];
  out[i*64+lane]=fmaxf(y,0.0f);
}

// ---- Second GCN aggregate + bias + residual (out = 2x + gcn2). ----
__global__ __launch_bounds__(256) void agg2_kernel(const float* __restrict__ h,
    const float* __restrict__ ew, const float* __restrict__ dis, const int* __restrict__ knn,
    const float* __restrict__ bias, const float* __restrict__ x,
    float* __restrict__ out){
  int wave=threadIdx.x>>6, lane=threadIdx.x&63;
  int i=blockIdx.x*4+wave;
  float di=dis[i];
  float acc=h[i*64+lane]*(di*di);
  #pragma unroll
  for(int m=0;m<3;m++){
    int s=knn[i*3+m];
    acc+=h[s*64+lane]*(dis[s]*ew[i*3+m]*di);
  }
  acc+=bias[lane];
  float xv=x[i*64+lane];
  out[i*64+lane]=(acc+xv)+xv;  // (gcn2 + x) + shortcut, shortcut == x
}

extern "C" void kernel_launch(void* const* d_in, const int* in_sizes, int n_in,
                              void* d_out, int out_size, void* d_ws, size_t ws_size,
                              hipStream_t stream){
  const float* feat  =(const float*)d_in[0];
  // d_in[1] edge_index_tran, d_in[2] edge_attr_rpe, d_in[3] norm_index: unused by reference
  const float* coords=(const float*)d_in[4];
  const float* g1 =(const float*)d_in[5];
  const float* b1n=(const float*)d_in[6];
  const float* g2 =(const float*)d_in[7];
  const float* b2n=(const float*)d_in[8];
  const float* gg =(const float*)d_in[9];
  const float* gb =(const float*)d_in[10];
  const float* W1 =(const float*)d_in[11];
  const float* bb1=(const float*)d_in[12];
  const float* W2 =(const float*)d_in[13];
  const float* bb2=(const float*)d_in[14];
  float* out=(float*)d_out;

  char* ws=(char*)d_ws;
  size_t o=0;
  float*  x      =(float*) (ws+o); o+=(size_t)N*64*4;    // post-LN2 features
  float*  h      =(float*) (ws+o); o+=(size_t)N*64*4;    // GEMM output (reused)
  float*  a1     =(float*) (ws+o); o+=(size_t)N*64*4;    // activated GCN1 output
  float*  xn     =(float*) (ws+o); o+=(size_t)N*4;       // row norms of x
  float*  ew     =(float*) (ws+o); o+=(size_t)N*3*4;     // knn edge weights
  float*  dis    =(float*) (ws+o); o+=(size_t)N*4;       // 1/sqrt(deg)
  int*    knn    =(int*)   (ws+o); o+=(size_t)N*3*4;     // neighbor indices
  float4* c4     =(float4*)(ws+o); o+=(size_t)N*16;      // (x,y,z,sq) original order
  float4* sc4    =(float4*)(ws+o); o+=(size_t)N*16;      // cell-sorted
  int*    sidx   =(int*)   (ws+o); o+=(size_t)N*4;       // sorted -> original
  int*    flag   =(int*)   (ws+o); o+=(size_t)N*4;       // needs-fallback flags
  int*    cellCnt=(int*)   (ws+o); o+=(size_t)NCELL*4;
  int*    cellSt =(int*)   (ws+o); o+=(size_t)(NCELL+1)*4;
  int*    cellCur=(int*)   (ws+o); o+=(size_t)NCELL*4;
  (void)ws_size; (void)in_sizes; (void)n_in; (void)out_size;

  hipMemsetAsync(cellCnt,0,NCELL*4,stream);
  hipLaunchKernelGGL(ln_kernel,     dim3(N/4),   dim3(256), 0, stream, feat,g1,b1n,g2,b2n,coords,x,xn,c4,cellCnt);
  hipLaunchKernelGGL(scan_kernel,   dim3(1),     dim3(256), 0, stream, cellCnt,cellSt,cellCur);
  hipLaunchKernelGGL(scatter_kernel,dim3(N/256), dim3(256), 0, stream, c4,cellCur,sc4,sidx);
  hipLaunchKernelGGL(knn_grid,      dim3(N*4/256),dim3(256),0, stream, sc4,sidx,cellSt,knn,flag);
  hipLaunchKernelGGL(knn_fb,        dim3(N/256), dim3(256), 0, stream, c4,flag,knn);
  hipLaunchKernelGGL(ew_kernel,     dim3(N/4),   dim3(256), 0, stream, x,xn,knn,ew,dis);
  hipLaunchKernelGGL(gemm64,        dim3(N/16),  dim3(256), 0, stream, x,W1,h);
  hipLaunchKernelGGL(agg1_kernel,   dim3(N/4),   dim3(256), 0, stream, h,ew,dis,knn,bb1,gg,gb,a1);
  hipLaunchKernelGGL(gemm64,        dim3(N/16),  dim3(256), 0, stream, a1,W2,h);
  hipLaunchKernelGGL(agg2_kernel,   dim3(N/4),   dim3(256), 0, stream, h,ew,dis,knn,bb2,x,out);
}